// Round 4
// baseline (214.151 us; speedup 1.0000x reference)
//
#include <hip/hip_runtime.h>

// ---------------------------------------------------------------------------
// IntraModalityEnhance — fp32 in/out, bf16 MFMA internals.
// B=2, S=2048, D=1024, H=16, HD=64, E=1024, W=31 (+pos,+fsq keys = 33).
//
//  prep       : ONE launch — x/fsq/pos -> bf16  +  Wq/Wk/Wv/Wo transposes
//  proj_gemm  : 288 blocks x 512 threads, BM=256 x BN=256, BK=64, 8-PHASE
//               counted-vmcnt schedule (T3+T4+T5): 4 phases/K-tile, one
//               half-tile (128x64) staged per phase via global_load_lds,
//               raw s_barrier pairs, vmcnt(4) once per K-tile (never 0 in
//               steady state), setprio(1) around each 16-MFMA cluster.
//               4 rotating half-slots per matrix = 128 KB LDS, 1 block/CU.
//               Chunk-XOR swizzle via pre-swizzled global source (rule #21).
//               XCD-chunked bijective swizzle (288 = 8*36, tn-fast).
//               [R2 lesson: __syncthreads-based dbuf drains vmcnt(0) at
//                every barrier -> raw s_barrier + explicit counted waits.]
//  attn_tile  : block=(b,h,32 s); DMA staging, MFMA QK^T/PV; softmax split
//               across 64 threads (pair shfl combine).
//  out_gemm   : BM=64, BN=128, BK=128 single-buffer + XCD swizzle (R1 config,
//               measured −9 µs vs no-swizzle; dbuf version regressed).
// ---------------------------------------------------------------------------

typedef __attribute__((ext_vector_type(8))) short bf16x8;
typedef __attribute__((ext_vector_type(4))) float f32x4;
typedef unsigned short u16;
typedef unsigned int u32;
typedef unsigned long long u64;

__device__ __forceinline__ float bf2f(u16 u) {
  union { u32 i; float f; } v; v.i = ((u32)u) << 16; return v.f;
}
__device__ __forceinline__ u16 f2bf(float f) {
  union { float f; u32 i; } v; v.f = f;
  u32 r = v.i + 0x7fffu + ((v.i >> 16) & 1u);
  return (u16)(r >> 16);
}
__device__ __forceinline__ float2 unpk(u32 u) {
  union { u32 i; float f; } lo, hi;
  lo.i = u << 16; hi.i = u & 0xffff0000u;
  return make_float2(lo.f, hi.f);
}
__device__ __forceinline__ float dot8(uint4 a, uint4 b) {
  float s = 0.f;
  { float2 x = unpk(a.x), y = unpk(b.x); s += x.x*y.x + x.y*y.y; }
  { float2 x = unpk(a.y), y = unpk(b.y); s += x.x*y.x + x.y*y.y; }
  { float2 x = unpk(a.z), y = unpk(b.z); s += x.x*y.x + x.y*y.y; }
  { float2 x = unpk(a.w), y = unpk(b.w); s += x.x*y.x + x.y*y.y; }
  return s;
}
__device__ __forceinline__ void gload_lds16(const u16* g, u16* l) {
  __builtin_amdgcn_global_load_lds((const __attribute__((address_space(1))) void*)(g),
                                   (__attribute__((address_space(3))) void*)(l),
                                   16, 0, 0);
}
__device__ __forceinline__ uint4 pack8(float4 a, float4 b) {
  union { u16 h[8]; uint4 q; } u;
  u.h[0] = f2bf(a.x); u.h[1] = f2bf(a.y); u.h[2] = f2bf(a.z); u.h[3] = f2bf(a.w);
  u.h[4] = f2bf(b.x); u.h[5] = f2bf(b.y); u.h[6] = f2bf(b.z); u.h[7] = f2bf(b.w);
  return u.q;
}

// ---------------------------------------------------------------------------
__device__ __forceinline__ void transpose_body(const float* src, u16* dst,
                                               int R, int C, int r0, int c0) {
  __shared__ u16 tile[64][72];
  int t = threadIdx.x;
#pragma unroll
  for (int i = 0; i < 16; ++i) {
    int idx = i * 256 + t;
    int r = idx >> 6, c = idx & 63;
    tile[r][c] = f2bf(src[(size_t)(r0 + r) * C + (c0 + c)]);
  }
  __syncthreads();
#pragma unroll
  for (int i = 0; i < 16; ++i) {
    int idx = i * 256 + t;
    int c = idx >> 6, r = idx & 63;
    dst[(size_t)(c0 + c) * R + (r0 + r)] = tile[r][c];
  }
}

// ONE launch: blocks 0..4095 convert x/fsq/pos; 4096..5119 transpose weights.
__global__ __launch_bounds__(256) void prep(const float* __restrict__ x,
                                            const float* __restrict__ fsq,
                                            const float* __restrict__ pos,
                                            const float* __restrict__ Wq,
                                            const float* __restrict__ Wk,
                                            const float* __restrict__ Wv,
                                            const float* __restrict__ Wo,
                                            u16* __restrict__ xb,
                                            u16* __restrict__ fsqb,
                                            u16* __restrict__ posb,
                                            u16* __restrict__ WqT,
                                            u16* __restrict__ WkT,
                                            u16* __restrict__ WvT,
                                            u16* __restrict__ WoT) {
  int bid = blockIdx.x;
  if (bid < 4096) {
    int i = bid * 256 + threadIdx.x;
    const float* src; u16* dst; int off;
    if (i < 524288)      { src = x;   dst = xb;   off = i; }
    else if (i < 786432) { src = fsq; dst = fsqb; off = i - 524288; }
    else                 { src = pos; dst = posb; off = i - 786432; }
    float4 a = ((const float4*)src)[2 * off];
    float4 b = ((const float4*)src)[2 * off + 1];
    ((uint4*)dst)[off] = pack8(a, b);
  } else {
    int id = bid - 4096;
    int z = id >> 8, rest = id & 255;
    int xx = rest & 15, yy = rest >> 4;
    if (z < 3) {
      const float* s = (z == 0) ? Wq : (z == 1) ? Wk : Wv;
      u16* d = (z == 0) ? WqT : (z == 1) ? WkT : WvT;
      size_t off = (size_t)xx * 65536;    // head * 1024 * 64
      transpose_body(s + off, d + off, 1024, 64, yy * 64, 0);
    } else {
      transpose_body(Wo, WoT, 1024, 1024, yy * 64, xx * 64);
    }
  }
}

// ---------------------------------------------------------------------------
// proj_gemm: 288 blocks x 512 threads, BM=256 x BN=256, BK=64, 8-phase.
//   lb < 256 : K/V proj. tm = lb>>3 (x tiles 0..15 | fsq 16..23 | pos 24..31),
//              tn = lb&7 (tn<4 -> K cols tn*256; tn>=4 -> V cols (tn-4)*256).
//   lb >= 256: Q proj (fsq @ WqT), 8 tm x 4 tn.
//
// Pipeline (paper-verified FIFO accounting):
//   stage stream per iter kt: φ0 B0(kt+1), φ1 B1(kt+1), φ2 A0(kt+2),
//   φ3 A1(kt+2); boundary s_waitcnt vmcnt(4) at φ3 retires {A(kt+1),B(kt+1)}
//   (the 8 oldest of 12 in flight) leaving A(kt+2) in flight.  Slot reuse is
//   separated from last reads by >=1 phase barrier in every case.
// ---------------------------------------------------------------------------
__global__ __launch_bounds__(512) void proj_gemm(const u16* __restrict__ xb,
                                                 const u16* __restrict__ fsqb,
                                                 const u16* __restrict__ posb,
                                                 const u16* __restrict__ WkT,
                                                 const u16* __restrict__ WvT,
                                                 const u16* __restrict__ WqT,
                                                 const float* __restrict__ bk,
                                                 const float* __restrict__ bv,
                                                 const float* __restrict__ bq,
                                                 u16* __restrict__ Kp,
                                                 u16* __restrict__ VpT,
                                                 u16* __restrict__ Vd,
                                                 u16* __restrict__ Qp) {
  __shared__ u16 AS[4][8192];   // 4 rotating A half-slots (128x64), 64 KB
  __shared__ u16 BS[4][8192];   // 4 rotating B half-slots, 64 KB

  const int bid = blockIdx.x;
  const int lb = (bid & 7) * 36 + (bid >> 3);   // XCD chunk swizzle (bijective)
  const int tid = threadIdx.x, lane = tid & 63, wave = tid >> 6;  // 8 waves
  const int row16 = lane & 15, quad = lane >> 4;
  const int wr = wave >> 2, wc = wave & 3;      // 2M x 4N wave grid
  const int bhalf = wc >> 1, bloc = (wc & 1) * 64;

  const u16 *Ap, *BT;
  const float* bias;
  u16* Crm = nullptr;   // row-major destination (Kp / Vd / Qp)
  u16* Cvt = nullptr;   // transposed V destination (VpT)
  int noff = 0, tmb = 0;

  if (lb < 256) {
    int tm = lb >> 3, tn = lb & 7;
    if (tm < 16)      Ap = xb   + (size_t)tm * 262144;
    else if (tm < 24) Ap = fsqb + (size_t)(tm - 16) * 262144;
    else              Ap = posb + (size_t)(tm - 24) * 262144;
    if (tn < 4) {
      BT = WkT + (size_t)(tn * 256) * 1024;
      bias = bk;
      Crm = Kp + (size_t)tm * 262144;
      noff = tn * 256;
    } else {
      BT = WvT + (size_t)((tn - 4) * 256) * 1024;
      bias = bv;
      noff = (tn - 4) * 256;
      if (tm < 16) { Cvt = VpT; tmb = tm * 256; }
      else         { Crm = Vd + (size_t)(tm - 16) * 262144; }
    }
  } else {
    int q = lb - 256;
    int tm = q >> 2, tn = q & 3;
    Ap = fsqb + (size_t)tm * 262144;
    BT = WqT + (size_t)(tn * 256) * 1024;
    bias = bq;
    Crm = Qp + (size_t)tm * 262144;
    noff = tn * 256;
  }

  // stage one 128x64 half-tile: dest linear, src chunk pre-swizzled (XOR)
  auto stage_half = [&](const u16* src, u16* dst) {
#pragma unroll
    for (int j = 0; j < 2; ++j) {
      int slot = j * 512 + wave * 64 + lane;
      int r = slot >> 3, cp = slot & 7;
      gload_lds16(src + (size_t)r * 1024 + ((cp ^ (r & 7)) << 3),
                  dst + ((j * 512 + wave * 64) << 3));
    }
  };
  // read a bf16x8 fragment at (local row R, k-chunk c) with matching XOR
  auto frag = [&](const u16* slot, int R, int c) -> bf16x8 {
    return *(const bf16x8*)&slot[(R * 8 + (c ^ (R & 7))) * 8];
  };

  f32x4 acc[8][4] = {};

  // ---- prologue: A0(0),A1(0),B0(0),B1(0),A0(1),A1(1) ----
  stage_half(Ap,                AS[0]);
  stage_half(Ap + 131072,       AS[1]);
  stage_half(BT,                BS[0]);
  stage_half(BT + 131072,       BS[1]);
  stage_half(Ap + 64,           AS[2]);
  stage_half(Ap + 131072 + 64,  AS[3]);
  asm volatile("s_waitcnt vmcnt(4)" ::: "memory");   // K-tile 0 landed
  __builtin_amdgcn_sched_barrier(0);
  __builtin_amdgcn_s_barrier();

  for (int kt = 0; kt < 16; ++kt) {
    const u16* As_ = AS[(2 * kt + wr) & 3];
    const u16* Bs_ = BS[(2 * kt + bhalf) & 3];
    const bool stB = (kt + 1 < 16);
    const bool stA = (kt + 2 < 16);

    bf16x8 a_lo[4][2], a_hi[4][2], bf0[2][2], bf1[2][2];

    // ---- phase 0: read a_lo + b01; stage B0(kt+1); MFMA (m0..3 x n0..1) ----
#pragma unroll
    for (int i = 0; i < 4; ++i)
#pragma unroll
      for (int ks = 0; ks < 2; ++ks)
        a_lo[i][ks] = frag(As_, i * 16 + row16, ks * 4 + quad);
#pragma unroll
    for (int j2 = 0; j2 < 2; ++j2)
#pragma unroll
      for (int ks = 0; ks < 2; ++ks)
        bf0[j2][ks] = frag(Bs_, bloc + j2 * 16 + row16, ks * 4 + quad);
    if (stB) stage_half(BT + (size_t)(kt + 1) * 64, BS[(2 * kt + 2) & 3]);
    __builtin_amdgcn_s_barrier();
    __builtin_amdgcn_s_setprio(1);
#pragma unroll
    for (int i = 0; i < 4; ++i)
#pragma unroll
      for (int j2 = 0; j2 < 2; ++j2)
#pragma unroll
        for (int ks = 0; ks < 2; ++ks)
          acc[i][j2] = __builtin_amdgcn_mfma_f32_16x16x32_bf16(
              a_lo[i][ks], bf0[j2][ks], acc[i][j2], 0, 0, 0);
    __builtin_amdgcn_s_setprio(0);
    __builtin_amdgcn_s_barrier();

    // ---- phase 1: read a_hi + b23; stage B1(kt+1); MFMA (m0..3 x n2..3) ----
#pragma unroll
    for (int i = 0; i < 4; ++i)
#pragma unroll
      for (int ks = 0; ks < 2; ++ks)
        a_hi[i][ks] = frag(As_, 64 + i * 16 + row16, ks * 4 + quad);
#pragma unroll
    for (int j2 = 0; j2 < 2; ++j2)
#pragma unroll
      for (int ks = 0; ks < 2; ++ks)
        bf1[j2][ks] = frag(Bs_, bloc + (j2 + 2) * 16 + row16, ks * 4 + quad);
    if (stB) stage_half(BT + 131072 + (size_t)(kt + 1) * 64, BS[(2 * kt + 3) & 3]);
    __builtin_amdgcn_s_barrier();
    __builtin_amdgcn_s_setprio(1);
#pragma unroll
    for (int i = 0; i < 4; ++i)
#pragma unroll
      for (int j2 = 0; j2 < 2; ++j2)
#pragma unroll
        for (int ks = 0; ks < 2; ++ks)
          acc[i][j2 + 2] = __builtin_amdgcn_mfma_f32_16x16x32_bf16(
              a_lo[i][ks], bf1[j2][ks], acc[i][j2 + 2], 0, 0, 0);
    __builtin_amdgcn_s_setprio(0);
    __builtin_amdgcn_s_barrier();

    // ---- phase 2: re-read b01; stage A0(kt+2); MFMA (m4..7 x n0..1) ----
#pragma unroll
    for (int j2 = 0; j2 < 2; ++j2)
#pragma unroll
      for (int ks = 0; ks < 2; ++ks)
        bf0[j2][ks] = frag(Bs_, bloc + j2 * 16 + row16, ks * 4 + quad);
    if (stA) stage_half(Ap + (size_t)(kt + 2) * 64, AS[(2 * kt) & 3]);
    __builtin_amdgcn_s_barrier();
    __builtin_amdgcn_s_setprio(1);
#pragma unroll
    for (int i = 0; i < 4; ++i)
#pragma unroll
      for (int j2 = 0; j2 < 2; ++j2)
#pragma unroll
        for (int ks = 0; ks < 2; ++ks)
          acc[i + 4][j2] = __builtin_amdgcn_mfma_f32_16x16x32_bf16(
              a_hi[i][ks], bf0[j2][ks], acc[i + 4][j2], 0, 0, 0);
    __builtin_amdgcn_s_setprio(0);
    __builtin_amdgcn_s_barrier();

    // ---- phase 3: re-read b23; stage A1(kt+2); boundary vmcnt; MFMA ----
#pragma unroll
    for (int j2 = 0; j2 < 2; ++j2)
#pragma unroll
      for (int ks = 0; ks < 2; ++ks)
        bf1[j2][ks] = frag(Bs_, bloc + (j2 + 2) * 16 + row16, ks * 4 + quad);
    if (stA) stage_half(Ap + 131072 + (size_t)(kt + 2) * 64, AS[(2 * kt + 1) & 3]);
    if (kt <= 13) {
      asm volatile("s_waitcnt vmcnt(4)" ::: "memory");   // retire A(kt+1),B(kt+1)
    } else if (kt == 14) {
      asm volatile("s_waitcnt vmcnt(0)" ::: "memory");   // tail drain
    }
    __builtin_amdgcn_sched_barrier(0);
    __builtin_amdgcn_s_barrier();
    __builtin_amdgcn_s_setprio(1);
#pragma unroll
    for (int i = 0; i < 4; ++i)
#pragma unroll
      for (int j2 = 0; j2 < 2; ++j2)
#pragma unroll
        for (int ks = 0; ks < 2; ++ks)
          acc[i + 4][j2 + 2] = __builtin_amdgcn_mfma_f32_16x16x32_bf16(
              a_hi[i][ks], bf1[j2][ks], acc[i + 4][j2 + 2], 0, 0, 0);
    __builtin_amdgcn_s_setprio(0);
    __builtin_amdgcn_s_barrier();
  }

  // ---- epilogue ----
  if (Cvt) {
#pragma unroll
    for (int j2 = 0; j2 < 4; ++j2) {
      int nv = noff + wc * 64 + j2 * 16 + row16;
      float bb = bias[nv];
#pragma unroll
      for (int i = 0; i < 8; ++i) {
        int m0 = wr * 128 + i * 16 + quad * 4;
        union { u16 h[4]; u64 q; } o;
#pragma unroll
        for (int r = 0; r < 4; ++r) o.h[r] = f2bf(acc[i][j2][r] + bb);
        *(u64*)(Cvt + (size_t)nv * 4096 + tmb + m0) = o.q;
      }
    }
  } else {
#pragma unroll
    for (int j2 = 0; j2 < 4; ++j2) {
      int n = noff + wc * 64 + j2 * 16 + row16;
      float bb = bias[n];
#pragma unroll
      for (int i = 0; i < 8; ++i) {
        int m0 = wr * 128 + i * 16 + quad * 4;
#pragma unroll
        for (int r = 0; r < 4; ++r)
          Crm[(size_t)(m0 + r) * 1024 + n] = f2bf(acc[i][j2][r] + bb);
      }
    }
  }
}

// ---------------------------------------------------------------------------
// out_gemm: BM=64, BN=128, BK=128, single-buffer (R1 config) + XCD-chunked
// swizzle: each XCD chunk touches full WoT (2 MB) + 8 Att row-tiles (1 MB)
// = 3 MB resident in its 4 MB L2.  Measured −9 µs vs no-swizzle (R0->R1).
// ---------------------------------------------------------------------------
__global__ __launch_bounds__(256) void out_gemm(const u16* __restrict__ Att,
                                                const u16* __restrict__ WoT,
                                                const float* __restrict__ bo,
                                                float* __restrict__ Out) {
  __shared__ u16 As[64 * 128];    // 16 KB
  __shared__ u16 Bs[128 * 128];   // 32 KB
  const int bid = blockIdx.x;
  const int lb = (bid & 7) * 64 + (bid >> 3);   // XCD chunk swizzle (bijective)
  const int tile_n = (lb & 7) * 128;
  const int tm = lb >> 3;
  const u16* Ap = Att + (size_t)tm * 65536;
  float* Cp = Out + (size_t)tm * 65536;

  const int t = threadIdx.x, lane = t & 63, wave = t >> 6;
  const int wm = (wave >> 1) * 32, wn = (wave & 1) * 64;
  const int row16 = lane & 15, quad = lane >> 4;

  f32x4 acc[2][4] = {};

  for (int k0 = 0; k0 < 1024; k0 += 128) {
    __syncthreads();
    // A: 64 rows x 16 chunks = 1024 chunks; wave covers rows wave*16..+15
#pragma unroll
    for (int j = 0; j < 4; ++j) {
      int idx = wave * 256 + j * 64 + lane;
      int r = idx >> 4, c = (idx & 15) ^ (r & 15);
      gload_lds16(Ap + (size_t)r * 1024 + k0 + c * 8,
                  &As[wave * 2048 + j * 512]);
    }
    // B: 128 rows x 16 chunks = 2048 chunks; wave covers rows wave*32..+31
#pragma unroll
    for (int j = 0; j < 8; ++j) {
      int idx = wave * 512 + j * 64 + lane;
      int r = idx >> 4, c = (idx & 15) ^ (r & 15);
      gload_lds16(WoT + (size_t)(tile_n + r) * 1024 + k0 + c * 8,
                  &Bs[wave * 4096 + j * 512]);
    }
    __syncthreads();

#pragma unroll
    for (int kb = 0; kb < 4; ++kb) {
      bf16x8 a_frag[2], b_frag[4];
#pragma unroll
      for (int i = 0; i < 2; ++i) {
        int R = wm + i * 16 + row16, c = kb * 4 + quad;
        a_frag[i] = *(const bf16x8*)&As[(R * 16 + (c ^ (R & 15))) * 8];
      }
#pragma unroll
      for (int j = 0; j < 4; ++j) {
        int R = wn + j * 16 + row16, c = kb * 4 + quad;
        b_frag[j] = *(const bf16x8*)&Bs[(R * 16 + (c ^ (R & 15))) * 8];
      }
#pragma unroll
      for (int i = 0; i < 2; ++i)
#pragma unroll
        for (int j = 0; j < 4; ++j)
          acc[i][j] = __builtin_amdgcn_mfma_f32_16x16x32_bf16(
              a_frag[i], b_frag[j], acc[i][j], 0, 0, 0);
    }
  }

#pragma unroll
  for (int j = 0; j < 4; ++j) {
    int n = tile_n + wn + j * 16 + row16;
    float bb = bo[n];
#pragma unroll
    for (int i = 0; i < 2; ++i) {
      int m0 = wm + i * 16 + quad * 4;
#pragma unroll
      for (int r = 0; r < 4; ++r)
        Cp[(size_t)(m0 + r) * 1024 + n] = acc[i][j][r] + bb;
    }
  }
}

// ---------------------------------------------------------------------------
// MFMA attention tile: block = (b, h, 32 s), ~35 KB LDS.  Softmax split over
// 64 threads (lane pairs, shfl_xor combine).
// ---------------------------------------------------------------------------
#define QS   0
#define KPS  2304
#define KFS  4608
#define KWS  6912
#define VTS  11008
#define SMT  15104

__global__ __launch_bounds__(256) void attn_tile(const u16* __restrict__ Qp,
                                                 const u16* __restrict__ Kp,
                                                 const u16* __restrict__ VpT,
                                                 const u16* __restrict__ Vd,
                                                 const float* __restrict__ bk,
                                                 const float* __restrict__ bv,
                                                 u16* __restrict__ Att) {
  __shared__ u16 sm[SMT];
  __shared__ float smP[32 * 36];

  const int t = threadIdx.x;
  const int bid = blockIdx.x;
  const int s0 = (bid & 63) * 32;
  const int h  = (bid >> 6) & 15;
  const int b  = bid >> 10;
  const int lane = t & 63, wave = t >> 6;
  const int row16 = lane & 15, quad = lane >> 4;
  const int hcol = h * 64;

  { int w = t >> 3, oct = t & 7;
    *(uint4*)&sm[QS + w * 72 + oct * 8] =
        *(const uint4*)(Qp + (size_t)(s0 + w) * 1024 + hcol + oct * 8); }
  { int r = t >> 3, oct = t & 7;
    *(uint4*)&sm[KPS + r * 72 + oct * 8] =
        *(const uint4*)(Kp + (size_t)(6144 + s0 + r) * 1024 + hcol + oct * 8);
    *(uint4*)&sm[KFS + r * 72 + oct * 8] =
        *(const uint4*)(Kp + (size_t)(4096 + s0 + r) * 1024 + hcol + oct * 8); }

  const bool boundary = (s0 == 0) || (s0 == 2016);
  if (!boundary) {
#pragma unroll
    for (int i = 0; i < 2; ++i) {
      int task = i * 256 + t;
      int w = task >> 3, oct = task & 7;
      gload_lds16(Kp + (size_t)(b * 2048 + s0 + w - 16) * 1024 + hcol + oct * 8,
                  &sm[KWS + (i * 256 + wave * 64) * 8]);
      int e = w;
      gload_lds16(VpT + (size_t)(hcol + e) * 4096 + (b * 2048 + s0 - 16) + oct * 8,
                  &sm[VTS + (i * 256 + wave * 64) * 8]);
    }
  } else {
#pragma unroll
    for (int i = 0; i < 2; ++i) {
      int task = i * 256 + t;
      int w = task >> 3, oct = task & 7;
      int g = s0 + w - 16;
      uint4 kv;
      if ((unsigned)g < 2048u)
        kv = *(const uint4*)(Kp + (size_t)(b * 2048 + g) * 1024 + hcol + oct * 8);
      else
        kv = pack8(*(const float4*)(bk + hcol + oct * 8),
                   *(const float4*)(bk + hcol + oct * 8 + 4));
      *(uint4*)&sm[KWS + w * 64 + oct * 8] = kv;

      int e = w;
      int g0 = s0 + oct * 8 - 16;
      uint4 vv;
      if (g0 >= 0 && g0 + 7 < 2048)
        vv = *(const uint4*)(VpT + (size_t)(hcol + e) * 4096 + (b * 2048 + g0));
      else {
        u16 hb = f2bf(bv[hcol + e]);
        u32 pp = (u32)hb | ((u32)hb << 16);
        vv = make_uint4(pp, pp, pp, pp);
      }
      *(uint4*)&sm[VTS + e * 64 + oct * 8] = vv;
    }
  }
  __syncthreads();

  {
    f32x4 accS[2] = {};
#pragma unroll
    for (int kc = 0; kc < 2; ++kc) {
      bf16x8 bf_ = *(const bf16x8*)&sm[KWS + (wave * 16 + row16) * 64 + kc * 32 + quad * 8];
#pragma unroll
      for (int mi = 0; mi < 2; ++mi) {
        bf16x8 af = *(const bf16x8*)&sm[QS + (mi * 16 + row16) * 72 + kc * 32 + quad * 8];
        accS[mi] = __builtin_amdgcn_mfma_f32_16x16x32_bf16(af, bf_, accS[mi], 0, 0, 0);
      }
    }
#pragma unroll
    for (int mi = 0; mi < 2; ++mi)
#pragma unroll
      for (int r = 0; r < 4; ++r) {
        int s = mi * 16 + quad * 4 + r;
        int w = wave * 16 + row16;
        int d = w - s;
        if (d >= 1 && d <= 31) smP[s * 36 + d - 1] = accS[mi][r] * 0.125f;
      }
  }
  if (t < 64) {
    int s = t >> 1, which = t & 1;
    int base = (which == 0) ? KPS : KFS;
    float a = 0.f;
#pragma unroll
    for (int c = 0; c < 8; ++c)
      a += dot8(*(const uint4*)&sm[QS + s * 72 + c * 8],
                *(const uint4*)&sm[base + s * 72 + c * 8]);
    smP[s * 36 + 31 + which] = a * 0.125f;
  }
  __syncthreads();

  // ---- softmax: 64 threads, lane pair (2s, 2s+1) splits 33 keys 17/16 ----
  if (t < 64) {
    const int s = t >> 1, half = t & 1;
    const int kb_ = half * 17;          // 0 or 17
    float vals[17];
#pragma unroll
    for (int k = 0; k < 17; ++k) {
      int kk = kb_ + k;
      vals[k] = (kk < 33) ? smP[s * 36 + kk] : -1e30f;
    }
    float mx = -1e30f;
#pragma unroll
    for (int k = 0; k < 17; ++k) mx = fmaxf(mx, vals[k]);
    mx = fmaxf(mx, __shfl_xor(mx, 1, 64));
    float sum = 0.f;
#pragma unroll
    for (int k = 0; k < 17; ++k) { vals[k] = __expf(vals[k] - mx); sum += vals[k]; }
    sum += __shfl_xor(sum, 1, 64);
    const float inv = 1.f / sum;
    u32* prow = (u32*)&sm[QS + s * 72];
#pragma unroll
    for (int j = 0; j < 16; ++j) prow[half * 16 + j] = 0;   // zero cols 0..63
    // (same-wave LDS ops are ordered: zeros complete before band writes)
#pragma unroll
    for (int k = 0; k < 17; ++k) {
      int kk = kb_ + k;
      if (kk < 31)      sm[QS + s * 72 + (s + 1 + kk)] = f2bf(vals[k] * inv);
      else if (kk < 33) smP[s * 36 + 2 + kk] = vals[k] * inv;  // 31->33, 32->34
    }
  }
  __syncthreads();

  {
    f32x4 accO[2] = {};
#pragma unroll
    for (int kc = 0; kc < 2; ++kc) {
      bf16x8 bf_ = *(const bf16x8*)&sm[VTS + (wave * 16 + row16) * 64 + kc * 32 + quad * 8];
#pragma unroll
      for (int mi = 0; mi < 2; ++mi) {
        bf16x8 af = *(const bf16x8*)&sm[QS + (mi * 16 + row16) * 72 + kc * 32 + quad * 8];
        accO[mi] = __builtin_amdgcn_mfma_f32_16x16x32_bf16(af, bf_, accO[mi], 0, 0, 0);
      }
    }
#pragma unroll
    for (int mi = 0; mi < 2; ++mi)
#pragma unroll
      for (int r = 0; r < 4; ++r) {
        int s = mi * 16 + quad * 4 + r;
        int e = wave * 16 + row16;
        float o = accO[mi][r]
                + smP[s * 36 + 33] * bf2f(Vd[(size_t)(2048 + s0 + s) * 1024 + hcol + e])
                + smP[s * 36 + 34] * bf2f(Vd[(size_t)(s0 + s) * 1024 + hcol + e]);
        Att[(size_t)(b * 2048 + s0 + s) * 1024 + hcol + e] = f2bf(o);
      }
  }
}

// ---------------------------------------------------------------------------
extern "C" void kernel_launch(void* const* d_in, const int* in_sizes, int n_in,
                              void* d_out, int out_size, void* d_ws, size_t ws_size,
                              hipStream_t stream) {
  (void)in_sizes; (void)n_in; (void)out_size; (void)ws_size;

  const float* x   = (const float*)d_in[0];
  const float* fsq = (const float*)d_in[1];
  const float* pos = (const float*)d_in[2];
  const float* Wq  = (const float*)d_in[3];
  const float* bq  = (const float*)d_in[4];
  const float* Wk  = (const float*)d_in[5];
  const float* bk  = (const float*)d_in[6];
  const float* Wv  = (const float*)d_in[7];
  const float* bv  = (const float*)d_in[8];
  const float* Wo  = (const float*)d_in[9];
  const float* bo  = (const float*)d_in[10];

  u16* ws = (u16*)d_ws;
  const size_t M1 = 1024 * 1024;
  u16* WqT  = ws + 0 * M1;   // 1M
  u16* WkT  = ws + 1 * M1;   // 1M
  u16* WvT  = ws + 2 * M1;   // 1M
  u16* WoT  = ws + 3 * M1;   // 1M
  u16* Qp   = ws + 4 * M1;   // 2M : 2048x1024
  u16* Kp   = ws + 6 * M1;   // 8M : 8192x1024 row-major
  u16* VpT  = ws + 14 * M1;  // 4M : 1024(n) x 4096(m, x-rows) TRANSPOSED
  u16* Vd   = ws + 18 * M1;  // 4M : 4096x1024 row-major (fsq-V; pos-V)
  u16* fsqb = ws + 22 * M1;  // 2M
  u16* posb = ws + 24 * M1;  // 2M
  u16* xb   = ws + 26 * M1;  // 4M : 4096x1024
  u16* Att  = ws + 22 * M1;  // 4M, aliases fsqb+posb (dead after proj_gemm)
  // peak 30M u16 = 60 MB

  prep<<<5120, 256, 0, stream>>>(x, fsq, pos, Wq, Wk, Wv, Wo,
                                 xb, fsqb, posb, WqT, WkT, WvT, WoT);

  proj_gemm<<<288, 512, 0, stream>>>(xb, fsqb, posb, WkT, WvT, WqT,
                                     bk, bv, bq, Kp, VpT, Vd, Qp);

  attn_tile<<<2048, 256, 0, stream>>>(Qp, Kp, VpT, Vd, bk, bv, Att);

  out_gemm<<<512, 256, 0, stream>>>(Att, WoT, bo, (float*)d_out);
}

// Round 5
// 193.676 us; speedup vs baseline: 1.1057x; 1.1057x over previous
//
#include <hip/hip_runtime.h>

// ---------------------------------------------------------------------------
// IntraModalityEnhance — fp32 in/out, bf16 MFMA internals.
// B=2, S=2048, D=1024, H=16, HD=64, E=1024, W=31 (+pos,+fsq keys = 33).
//
//  prep       : ONE launch — x/fsq/pos -> bf16  +  Wq/Wk/Wv/Wo transposes
//  proj_gemm  : R3 measured-best config: 576 blocks x 512 threads,
//               BM=128 x BN=256 (N = K-half || V-half), 2-barrier loop,
//               XCD-chunked bijective swizzle (576 = 8*72).  60.3 µs, 642 TF
//               = the 2-phase structural ceiling.  [R2: dbuf regressed;
//               R4: 256²/8-phase regressed via grid quantization 288/256
//               at 1 block/CU -> 56% CU-utilization cap.]
//  attn_tile  : block=(b,h,32 s); DMA staging, MFMA QK^T/PV.  NEW: extra-key
//               dot8 and softmax parallelized across ALL 256 threads
//               (was 64-thread serial; Common-mistake #6).
//  out_gemm   : BM=64, BN=128, BK=128 single-buffer + XCD swizzle (R1 config).
// ---------------------------------------------------------------------------

typedef __attribute__((ext_vector_type(8))) short bf16x8;
typedef __attribute__((ext_vector_type(4))) float f32x4;
typedef unsigned short u16;
typedef unsigned int u32;
typedef unsigned long long u64;

__device__ __forceinline__ float bf2f(u16 u) {
  union { u32 i; float f; } v; v.i = ((u32)u) << 16; return v.f;
}
__device__ __forceinline__ u16 f2bf(float f) {
  union { float f; u32 i; } v; v.f = f;
  u32 r = v.i + 0x7fffu + ((v.i >> 16) & 1u);
  return (u16)(r >> 16);
}
__device__ __forceinline__ float2 unpk(u32 u) {
  union { u32 i; float f; } lo, hi;
  lo.i = u << 16; hi.i = u & 0xffff0000u;
  return make_float2(lo.f, hi.f);
}
__device__ __forceinline__ float dot8(uint4 a, uint4 b) {
  float s = 0.f;
  { float2 x = unpk(a.x), y = unpk(b.x); s += x.x*y.x + x.y*y.y; }
  { float2 x = unpk(a.y), y = unpk(b.y); s += x.x*y.x + x.y*y.y; }
  { float2 x = unpk(a.z), y = unpk(b.z); s += x.x*y.x + x.y*y.y; }
  { float2 x = unpk(a.w), y = unpk(b.w); s += x.x*y.x + x.y*y.y; }
  return s;
}
__device__ __forceinline__ void gload_lds16(const u16* g, u16* l) {
  __builtin_amdgcn_global_load_lds((const __attribute__((address_space(1))) void*)(g),
                                   (__attribute__((address_space(3))) void*)(l),
                                   16, 0, 0);
}
__device__ __forceinline__ uint4 pack8(float4 a, float4 b) {
  union { u16 h[8]; uint4 q; } u;
  u.h[0] = f2bf(a.x); u.h[1] = f2bf(a.y); u.h[2] = f2bf(a.z); u.h[3] = f2bf(a.w);
  u.h[4] = f2bf(b.x); u.h[5] = f2bf(b.y); u.h[6] = f2bf(b.z); u.h[7] = f2bf(b.w);
  return u.q;
}

// ---------------------------------------------------------------------------
__device__ __forceinline__ void transpose_body(const float* src, u16* dst,
                                               int R, int C, int r0, int c0) {
  __shared__ u16 tile[64][72];
  int t = threadIdx.x;
#pragma unroll
  for (int i = 0; i < 16; ++i) {
    int idx = i * 256 + t;
    int r = idx >> 6, c = idx & 63;
    tile[r][c] = f2bf(src[(size_t)(r0 + r) * C + (c0 + c)]);
  }
  __syncthreads();
#pragma unroll
  for (int i = 0; i < 16; ++i) {
    int idx = i * 256 + t;
    int c = idx >> 6, r = idx & 63;
    dst[(size_t)(c0 + c) * R + (r0 + r)] = tile[r][c];
  }
}

// ONE launch: blocks 0..4095 convert x/fsq/pos; 4096..5119 transpose weights.
__global__ __launch_bounds__(256) void prep(const float* __restrict__ x,
                                            const float* __restrict__ fsq,
                                            const float* __restrict__ pos,
                                            const float* __restrict__ Wq,
                                            const float* __restrict__ Wk,
                                            const float* __restrict__ Wv,
                                            const float* __restrict__ Wo,
                                            u16* __restrict__ xb,
                                            u16* __restrict__ fsqb,
                                            u16* __restrict__ posb,
                                            u16* __restrict__ WqT,
                                            u16* __restrict__ WkT,
                                            u16* __restrict__ WvT,
                                            u16* __restrict__ WoT) {
  int bid = blockIdx.x;
  if (bid < 4096) {
    int i = bid * 256 + threadIdx.x;
    const float* src; u16* dst; int off;
    if (i < 524288)      { src = x;   dst = xb;   off = i; }
    else if (i < 786432) { src = fsq; dst = fsqb; off = i - 524288; }
    else                 { src = pos; dst = posb; off = i - 786432; }
    float4 a = ((const float4*)src)[2 * off];
    float4 b = ((const float4*)src)[2 * off + 1];
    ((uint4*)dst)[off] = pack8(a, b);
  } else {
    int id = bid - 4096;
    int z = id >> 8, rest = id & 255;
    int xx = rest & 15, yy = rest >> 4;
    if (z < 3) {
      const float* s = (z == 0) ? Wq : (z == 1) ? Wk : Wv;
      u16* d = (z == 0) ? WqT : (z == 1) ? WkT : WvT;
      size_t off = (size_t)xx * 65536;    // head * 1024 * 64
      transpose_body(s + off, d + off, 1024, 64, yy * 64, 0);
    } else {
      transpose_body(Wo, WoT, 1024, 1024, yy * 64, xx * 64);
    }
  }
}

// ---------------------------------------------------------------------------
__device__ __forceinline__ int swz(int R, int c) {   // BK=64: 8 chunks/row
  return (R * 8 + (c ^ (R & 7))) * 8;
}

// ---------------------------------------------------------------------------
// proj_gemm: 576 blocks x 512 threads, BM=128 x BN=256 (N = K-half||V-half).
// Proven R0/R3 2-barrier loop + XCD-chunked bijective swizzle (576 = 8*72).
// ---------------------------------------------------------------------------
__global__ __launch_bounds__(512) void proj_gemm(const u16* __restrict__ xb,
                                                 const u16* __restrict__ fsqb,
                                                 const u16* __restrict__ posb,
                                                 const u16* __restrict__ WkT,
                                                 const u16* __restrict__ WvT,
                                                 const u16* __restrict__ WqT,
                                                 const float* __restrict__ bk,
                                                 const float* __restrict__ bv,
                                                 const float* __restrict__ bq,
                                                 u16* __restrict__ Kp,
                                                 u16* __restrict__ VpT,
                                                 u16* __restrict__ Vd,
                                                 u16* __restrict__ Qp) {
  __shared__ u16 As[128 * 64];   // 16 KB
  __shared__ u16 Bs[256 * 64];   // 32 KB

  const int bid = blockIdx.x;
  const int lb = (bid & 7) * 72 + (bid >> 3);   // XCD chunk swizzle (bijective)
  const int t = threadIdx.x, lane = t & 63, wave = t >> 6;   // wave 0..7
  const int row16 = lane & 15, quad = lane >> 4;
  const int l8 = lane >> 3;
  const int cswz = (lane & 7) ^ l8;

  const u16 *Ap, *BTa, *BTb;
  const float *biasA, *biasB;
  u16 *C1, *C2rm;
  int c1_noff, c2_noff;
  bool c2_t = false;
  int tmb = 0;

  if (lb < 512) {
    int tm = lb >> 3, tn = lb & 7;
    if (tm < 32)      Ap = xb   + (size_t)tm * 131072;
    else if (tm < 48) Ap = fsqb + (size_t)(tm - 32) * 131072;
    else              Ap = posb + (size_t)(tm - 48) * 131072;
    BTa = WkT + (size_t)(tn * 128) * 1024;
    BTb = WvT + (size_t)(tn * 128) * 1024;
    biasA = bk; biasB = bv;
    C1 = Kp + (size_t)tm * 131072; c1_noff = tn * 128;
    c2_noff = tn * 128;
    if (tm < 32) { c2_t = true; tmb = tm * 128; C2rm = nullptr; }
    else         { C2rm = Vd + (size_t)(tm - 32) * 131072; }
  } else {
    int q = lb - 512;
    int tm = q >> 2, tn4 = q & 3;
    Ap  = fsqb + (size_t)tm * 131072;
    BTa = WqT + (size_t)(tn4 * 256) * 1024;
    BTb = WqT + (size_t)(tn4 * 256 + 128) * 1024;
    biasA = bq; biasB = bq;
    C1 = Qp + (size_t)tm * 131072;  c1_noff = tn4 * 256;
    C2rm = C1;                      c2_noff = tn4 * 256 + 128;
  }

  const int wm = (wave >> 2) * 64, wn = (wave & 3) * 64;
  f32x4 acc[4][4] = {};

  for (int k0 = 0; k0 < 1024; k0 += 64) {
    __syncthreads();
#pragma unroll
    for (int j = 0; j < 2; ++j) {
      int r = wave * 16 + j * 8 + l8;
      gload_lds16(Ap + (size_t)r * 1024 + k0 + cswz * 8,
                  &As[wave * 1024 + j * 512]);
    }
    const u16* Bsrc = (wave < 4) ? BTa : BTb;
    const int rb = (wave & 3) * 32;
#pragma unroll
    for (int j = 0; j < 4; ++j) {
      int r = rb + j * 8 + l8;
      gload_lds16(Bsrc + (size_t)r * 1024 + k0 + cswz * 8,
                  &Bs[wave * 2048 + j * 512]);
    }
    __syncthreads();

#pragma unroll
    for (int kb = 0; kb < 2; ++kb) {
      bf16x8 a_frag[4], b_frag[4];
#pragma unroll
      for (int i = 0; i < 4; ++i)
        a_frag[i] = *(const bf16x8*)&As[swz(wm + i * 16 + row16, kb * 4 + quad)];
#pragma unroll
      for (int j = 0; j < 4; ++j)
        b_frag[j] = *(const bf16x8*)&Bs[swz(wn + j * 16 + row16, kb * 4 + quad)];
#pragma unroll
      for (int i = 0; i < 4; ++i)
#pragma unroll
        for (int j = 0; j < 4; ++j)
          acc[i][j] = __builtin_amdgcn_mfma_f32_16x16x32_bf16(
              a_frag[i], b_frag[j], acc[i][j], 0, 0, 0);
    }
  }

  if (wn < 128) {
#pragma unroll
    for (int j = 0; j < 4; ++j) {
      int n = c1_noff + wn + j * 16 + row16;
      float bb = biasA[n];
#pragma unroll
      for (int i = 0; i < 4; ++i) {
        int m0 = wm + i * 16 + quad * 4;
#pragma unroll
        for (int r = 0; r < 4; ++r)
          C1[(size_t)(m0 + r) * 1024 + n] = f2bf(acc[i][j][r] + bb);
      }
    }
  } else if (c2_t) {
#pragma unroll
    for (int j = 0; j < 4; ++j) {
      int nv = c2_noff + (wn - 128) + j * 16 + row16;
      float bb = biasB[nv];
#pragma unroll
      for (int i = 0; i < 4; ++i) {
        int m0 = wm + i * 16 + quad * 4;
        union { u16 h[4]; u64 q; } o;
#pragma unroll
        for (int r = 0; r < 4; ++r) o.h[r] = f2bf(acc[i][j][r] + bb);
        *(u64*)(VpT + (size_t)nv * 4096 + tmb + m0) = o.q;
      }
    }
  } else {
#pragma unroll
    for (int j = 0; j < 4; ++j) {
      int nv = c2_noff + (wn - 128) + j * 16 + row16;
      float bb = biasB[nv];
#pragma unroll
      for (int i = 0; i < 4; ++i) {
        int m0 = wm + i * 16 + quad * 4;
#pragma unroll
        for (int r = 0; r < 4; ++r)
          C2rm[(size_t)(m0 + r) * 1024 + nv] = f2bf(acc[i][j][r] + bb);
      }
    }
  }
}

// ---------------------------------------------------------------------------
// out_gemm: BM=64, BN=128, BK=128, single-buffer (R1 config) + XCD-chunked
// swizzle: each XCD chunk touches full WoT (2 MB) + 8 Att row-tiles (1 MB)
// = 3 MB resident in its 4 MB L2.  Measured −9 µs vs no-swizzle (R0->R1).
// ---------------------------------------------------------------------------
__global__ __launch_bounds__(256) void out_gemm(const u16* __restrict__ Att,
                                                const u16* __restrict__ WoT,
                                                const float* __restrict__ bo,
                                                float* __restrict__ Out) {
  __shared__ u16 As[64 * 128];    // 16 KB
  __shared__ u16 Bs[128 * 128];   // 32 KB
  const int bid = blockIdx.x;
  const int lb = (bid & 7) * 64 + (bid >> 3);   // XCD chunk swizzle (bijective)
  const int tile_n = (lb & 7) * 128;
  const int tm = lb >> 3;
  const u16* Ap = Att + (size_t)tm * 65536;
  float* Cp = Out + (size_t)tm * 65536;

  const int t = threadIdx.x, lane = t & 63, wave = t >> 6;
  const int wm = (wave >> 1) * 32, wn = (wave & 1) * 64;
  const int row16 = lane & 15, quad = lane >> 4;

  f32x4 acc[2][4] = {};

  for (int k0 = 0; k0 < 1024; k0 += 128) {
    __syncthreads();
    // A: 64 rows x 16 chunks = 1024 chunks; wave covers rows wave*16..+15
#pragma unroll
    for (int j = 0; j < 4; ++j) {
      int idx = wave * 256 + j * 64 + lane;
      int r = idx >> 4, c = (idx & 15) ^ (r & 15);
      gload_lds16(Ap + (size_t)r * 1024 + k0 + c * 8,
                  &As[wave * 2048 + j * 512]);
    }
    // B: 128 rows x 16 chunks = 2048 chunks; wave covers rows wave*32..+31
#pragma unroll
    for (int j = 0; j < 8; ++j) {
      int idx = wave * 512 + j * 64 + lane;
      int r = idx >> 4, c = (idx & 15) ^ (r & 15);
      gload_lds16(WoT + (size_t)(tile_n + r) * 1024 + k0 + c * 8,
                  &Bs[wave * 4096 + j * 512]);
    }
    __syncthreads();

#pragma unroll
    for (int kb = 0; kb < 4; ++kb) {
      bf16x8 a_frag[2], b_frag[4];
#pragma unroll
      for (int i = 0; i < 2; ++i) {
        int R = wm + i * 16 + row16, c = kb * 4 + quad;
        a_frag[i] = *(const bf16x8*)&As[(R * 16 + (c ^ (R & 15))) * 8];
      }
#pragma unroll
      for (int j = 0; j < 4; ++j) {
        int R = wn + j * 16 + row16, c = kb * 4 + quad;
        b_frag[j] = *(const bf16x8*)&Bs[(R * 16 + (c ^ (R & 15))) * 8];
      }
#pragma unroll
      for (int i = 0; i < 2; ++i)
#pragma unroll
        for (int j = 0; j < 4; ++j)
          acc[i][j] = __builtin_amdgcn_mfma_f32_16x16x32_bf16(
              a_frag[i], b_frag[j], acc[i][j], 0, 0, 0);
    }
  }

#pragma unroll
  for (int j = 0; j < 4; ++j) {
    int n = tile_n + wn + j * 16 + row16;
    float bb = bo[n];
#pragma unroll
    for (int i = 0; i < 2; ++i) {
      int m0 = wm + i * 16 + quad * 4;
#pragma unroll
      for (int r = 0; r < 4; ++r)
        Cp[(size_t)(m0 + r) * 1024 + n] = acc[i][j][r] + bb;
    }
  }
}

// ---------------------------------------------------------------------------
// MFMA attention tile: block = (b, h, 32 s), ~35 KB LDS.
// Extra-key scores and softmax both use ALL 256 threads:
//   dot8 : 64 tasks (s, which) x 4-way HD split, shfl_xor(1,2) combine.
//   softmax: 32 rows x 8 lanes, <=5 keys/lane, shfl_xor(1,2,4) max/sum.
//   Explicit barrier between P-zeroing and cross-thread band writes.
// ---------------------------------------------------------------------------
#define QS   0
#define KPS  2304
#define KFS  4608
#define KWS  6912
#define VTS  11008
#define SMT  15104

__global__ __launch_bounds__(256) void attn_tile(const u16* __restrict__ Qp,
                                                 const u16* __restrict__ Kp,
                                                 const u16* __restrict__ VpT,
                                                 const u16* __restrict__ Vd,
                                                 const float* __restrict__ bk,
                                                 const float* __restrict__ bv,
                                                 u16* __restrict__ Att) {
  __shared__ u16 sm[SMT];
  __shared__ float smP[32 * 36];

  const int t = threadIdx.x;
  const int bid = blockIdx.x;
  const int s0 = (bid & 63) * 32;
  const int h  = (bid >> 6) & 15;
  const int b  = bid >> 10;
  const int lane = t & 63, wave = t >> 6;
  const int row16 = lane & 15, quad = lane >> 4;
  const int hcol = h * 64;

  { int w = t >> 3, oct = t & 7;
    *(uint4*)&sm[QS + w * 72 + oct * 8] =
        *(const uint4*)(Qp + (size_t)(s0 + w) * 1024 + hcol + oct * 8); }
  { int r = t >> 3, oct = t & 7;
    *(uint4*)&sm[KPS + r * 72 + oct * 8] =
        *(const uint4*)(Kp + (size_t)(6144 + s0 + r) * 1024 + hcol + oct * 8);
    *(uint4*)&sm[KFS + r * 72 + oct * 8] =
        *(const uint4*)(Kp + (size_t)(4096 + s0 + r) * 1024 + hcol + oct * 8); }

  const bool boundary = (s0 == 0) || (s0 == 2016);
  if (!boundary) {
#pragma unroll
    for (int i = 0; i < 2; ++i) {
      int task = i * 256 + t;
      int w = task >> 3, oct = task & 7;
      gload_lds16(Kp + (size_t)(b * 2048 + s0 + w - 16) * 1024 + hcol + oct * 8,
                  &sm[KWS + (i * 256 + wave * 64) * 8]);
      int e = w;
      gload_lds16(VpT + (size_t)(hcol + e) * 4096 + (b * 2048 + s0 - 16) + oct * 8,
                  &sm[VTS + (i * 256 + wave * 64) * 8]);
    }
  } else {
#pragma unroll
    for (int i = 0; i < 2; ++i) {
      int task = i * 256 + t;
      int w = task >> 3, oct = task & 7;
      int g = s0 + w - 16;
      uint4 kv;
      if ((unsigned)g < 2048u)
        kv = *(const uint4*)(Kp + (size_t)(b * 2048 + g) * 1024 + hcol + oct * 8);
      else
        kv = pack8(*(const float4*)(bk + hcol + oct * 8),
                   *(const float4*)(bk + hcol + oct * 8 + 4));
      *(uint4*)&sm[KWS + w * 64 + oct * 8] = kv;

      int e = w;
      int g0 = s0 + oct * 8 - 16;
      uint4 vv;
      if (g0 >= 0 && g0 + 7 < 2048)
        vv = *(const uint4*)(VpT + (size_t)(hcol + e) * 4096 + (b * 2048 + g0));
      else {
        u16 hb = f2bf(bv[hcol + e]);
        u32 pp = (u32)hb | ((u32)hb << 16);
        vv = make_uint4(pp, pp, pp, pp);
      }
      *(uint4*)&sm[VTS + e * 64 + oct * 8] = vv;
    }
  }
  __syncthreads();

  {
    f32x4 accS[2] = {};
#pragma unroll
    for (int kc = 0; kc < 2; ++kc) {
      bf16x8 bf_ = *(const bf16x8*)&sm[KWS + (wave * 16 + row16) * 64 + kc * 32 + quad * 8];
#pragma unroll
      for (int mi = 0; mi < 2; ++mi) {
        bf16x8 af = *(const bf16x8*)&sm[QS + (mi * 16 + row16) * 72 + kc * 32 + quad * 8];
        accS[mi] = __builtin_amdgcn_mfma_f32_16x16x32_bf16(af, bf_, accS[mi], 0, 0, 0);
      }
    }
#pragma unroll
    for (int mi = 0; mi < 2; ++mi)
#pragma unroll
      for (int r = 0; r < 4; ++r) {
        int s = mi * 16 + quad * 4 + r;
        int w = wave * 16 + row16;
        int d = w - s;
        if (d >= 1 && d <= 31) smP[s * 36 + d - 1] = accS[mi][r] * 0.125f;
      }
  }
  {
    // extra-key scores: 64 tasks (s, which) x 4-way c-split, all 256 threads
    int s = t >> 3, which = (t >> 2) & 1, cq = t & 3;
    int base = (which == 0) ? KPS : KFS;
    float a = 0.f;
#pragma unroll
    for (int c2 = 0; c2 < 2; ++c2) {
      int c = cq * 2 + c2;
      a += dot8(*(const uint4*)&sm[QS + s * 72 + c * 8],
                *(const uint4*)&sm[base + s * 72 + c * 8]);
    }
    a += __shfl_xor(a, 1, 64);
    a += __shfl_xor(a, 2, 64);
    if (cq == 0) smP[s * 36 + 31 + which] = a * 0.125f;
  }
  __syncthreads();

  // ---- softmax: 32 rows x 8 lanes; each lane handles keys part+8j (<=5) ----
  {
    const int s = t >> 3, part = t & 7;
    float vals[5];
    float mx = -1e30f;
#pragma unroll
    for (int j = 0; j < 5; ++j) {
      int k = part + 8 * j;
      if (k < 33) { float v = smP[s * 36 + k]; vals[j] = v; mx = fmaxf(mx, v); }
    }
    mx = fmaxf(mx, __shfl_xor(mx, 1, 64));
    mx = fmaxf(mx, __shfl_xor(mx, 2, 64));
    mx = fmaxf(mx, __shfl_xor(mx, 4, 64));
    float sum = 0.f;
#pragma unroll
    for (int j = 0; j < 5; ++j) {
      int k = part + 8 * j;
      if (k < 33) { vals[j] = __expf(vals[j] - mx); sum += vals[j]; }
    }
    sum += __shfl_xor(sum, 1, 64);
    sum += __shfl_xor(sum, 2, 64);
    sum += __shfl_xor(sum, 4, 64);
    const float inv = 1.f / sum;
    // zero this row's 64 P cols: 8 threads x 4 u32 words
    u32* prow = (u32*)&sm[QS + s * 72];
#pragma unroll
    for (int w_ = 0; w_ < 4; ++w_) prow[part * 4 + w_] = 0;
    __syncthreads();   // zeros visible before cross-thread band writes
#pragma unroll
    for (int j = 0; j < 5; ++j) {
      int k = part + 8 * j;
      if (k < 31)      sm[QS + s * 72 + (s + 1 + k)] = f2bf(vals[j] * inv);
      else if (k < 33) smP[s * 36 + 2 + k] = vals[j] * inv;  // 31->33, 32->34
    }
  }
  __syncthreads();

  {
    f32x4 accO[2] = {};
#pragma unroll
    for (int kc = 0; kc < 2; ++kc) {
      bf16x8 bf_ = *(const bf16x8*)&sm[VTS + (wave * 16 + row16) * 64 + kc * 32 + quad * 8];
#pragma unroll
      for (int mi = 0; mi < 2; ++mi) {
        bf16x8 af = *(const bf16x8*)&sm[QS + (mi * 16 + row16) * 72 + kc * 32 + quad * 8];
        accO[mi] = __builtin_amdgcn_mfma_f32_16x16x32_bf16(af, bf_, accO[mi], 0, 0, 0);
      }
    }
#pragma unroll
    for (int mi = 0; mi < 2; ++mi)
#pragma unroll
      for (int r = 0; r < 4; ++r) {
        int s = mi * 16 + quad * 4 + r;
        int e = wave * 16 + row16;
        float o = accO[mi][r]
                + smP[s * 36 + 33] * bf2f(Vd[(size_t)(2048 + s0 + s) * 1024 + hcol + e])
                + smP[s * 36 + 34] * bf2f(Vd[(size_t)(s0 + s) * 1024 + hcol + e]);
        Att[(size_t)(b * 2048 + s0 + s) * 1024 + hcol + e] = f2bf(o);
      }
  }
}

// ---------------------------------------------------------------------------
extern "C" void kernel_launch(void* const* d_in, const int* in_sizes, int n_in,
                              void* d_out, int out_size, void* d_ws, size_t ws_size,
                              hipStream_t stream) {
  (void)in_sizes; (void)n_in; (void)out_size; (void)ws_size;

  const float* x   = (const float*)d_in[0];
  const float* fsq = (const float*)d_in[1];
  const float* pos = (const float*)d_in[2];
  const float* Wq  = (const float*)d_in[3];
  const float* bq  = (const float*)d_in[4];
  const float* Wk  = (const float*)d_in[5];
  const float* bk  = (const float*)d_in[6];
  const float* Wv  = (const float*)d_in[7];
  const float* bv  = (const float*)d_in[8];
  const float* Wo  = (const float*)d_in[9];
  const float* bo  = (const float*)d_in[10];

  u16* ws = (u16*)d_ws;
  const size_t M1 = 1024 * 1024;
  u16* WqT  = ws + 0 * M1;   // 1M
  u16* WkT  = ws + 1 * M1;   // 1M
  u16* WvT  = ws + 2 * M1;   // 1M
  u16* WoT  = ws + 3 * M1;   // 1M
  u16* Qp   = ws + 4 * M1;   // 2M : 2048x1024
  u16* Kp   = ws + 6 * M1;   // 8M : 8192x1024 row-major
  u16* VpT  = ws + 14 * M1;  // 4M : 1024(n) x 4096(m, x-rows) TRANSPOSED
  u16* Vd   = ws + 18 * M1;  // 4M : 4096x1024 row-major (fsq-V; pos-V)
  u16* fsqb = ws + 22 * M1;  // 2M
  u16* posb = ws + 24 * M1;  // 2M
  u16* xb   = ws + 26 * M1;  // 4M : 4096x1024
  u16* Att  = ws + 22 * M1;  // 4M, aliases fsqb+posb (dead after proj_gemm)
  // peak 30M u16 = 60 MB

  prep<<<5120, 256, 0, stream>>>(x, fsq, pos, Wq, Wk, Wv, Wo,
                                 xb, fsqb, posb, WqT, WkT, WvT, WoT);

  proj_gemm<<<576, 512, 0, stream>>>(xb, fsqb, posb, WkT, WvT, WqT,
                                     bk, bv, bq, Kp, VpT, Vd, Qp);

  attn_tile<<<2048, 256, 0, stream>>>(Qp, Kp, VpT, Vd, bk, bv, Att);

  out_gemm<<<512, 256, 0, stream>>>(Att, WoT, bo, (float*)d_out);
}